// Round 1
// baseline (353.819 us; speedup 1.0000x reference)
//
#include <hip/hip_runtime.h>
#include <hip/hip_bf16.h>

#define N_NODES 50000
#define N_EDGES 800000
#define IN_F 256
#define HEADS 8
#define OUT_F 32
#define HF (HEADS * OUT_F)   // 256
#define SLOPE 0.2f

// ---------------------------------------------------------------------------
// Kernel 1: fp32 GEMM  C[M,256] = A[M,256] @ B[256,256]
// 64x64 tile, BK=16, 256 threads, 4x4 accumulators per thread.
// ---------------------------------------------------------------------------
#define BM 64
#define BN 64
#define BK 16

__global__ __launch_bounds__(256) void gemm_kernel(
    const float* __restrict__ A, const float* __restrict__ B,
    float* __restrict__ C, int M) {
  __shared__ float As[BK][BM];
  __shared__ float Bs[BK][BN];
  const int t = threadIdx.x;
  const int m0 = blockIdx.y * BM;
  const int n0 = blockIdx.x * BN;
  const int tm = (t >> 4) << 2;   // 0..60 step 4
  const int tn = (t & 15) << 2;   // 0..60 step 4

  float acc[4][4] = {};

  // A-tile load indices: 64x16 elements, 4 consecutive k's per thread
  const int a_row = (t * 4) >> 4;   // 0..63
  const int a_col = (t * 4) & 15;   // {0,4,8,12}
  // B-tile load indices: 16x64 elements
  const int b_row = t >> 4;         // 0..15
  const int b_col = (t & 15) << 2;  // 0..60 step 4

  for (int k0 = 0; k0 < IN_F; k0 += BK) {
    float4 a;
    if (m0 + a_row < M)
      a = *(const float4*)&A[(size_t)(m0 + a_row) * IN_F + k0 + a_col];
    else
      a = make_float4(0.f, 0.f, 0.f, 0.f);
    As[a_col + 0][a_row] = a.x;
    As[a_col + 1][a_row] = a.y;
    As[a_col + 2][a_row] = a.z;
    As[a_col + 3][a_row] = a.w;

    *(float4*)&Bs[b_row][b_col] =
        *(const float4*)&B[(size_t)(k0 + b_row) * HF + n0 + b_col];

    __syncthreads();

#pragma unroll
    for (int k = 0; k < BK; ++k) {
      float a0 = As[k][tm + 0], a1 = As[k][tm + 1];
      float a2 = As[k][tm + 2], a3 = As[k][tm + 3];
      float b0 = Bs[k][tn + 0], b1 = Bs[k][tn + 1];
      float b2 = Bs[k][tn + 2], b3 = Bs[k][tn + 3];
      acc[0][0] = fmaf(a0, b0, acc[0][0]);
      acc[0][1] = fmaf(a0, b1, acc[0][1]);
      acc[0][2] = fmaf(a0, b2, acc[0][2]);
      acc[0][3] = fmaf(a0, b3, acc[0][3]);
      acc[1][0] = fmaf(a1, b0, acc[1][0]);
      acc[1][1] = fmaf(a1, b1, acc[1][1]);
      acc[1][2] = fmaf(a1, b2, acc[1][2]);
      acc[1][3] = fmaf(a1, b3, acc[1][3]);
      acc[2][0] = fmaf(a2, b0, acc[2][0]);
      acc[2][1] = fmaf(a2, b1, acc[2][1]);
      acc[2][2] = fmaf(a2, b2, acc[2][2]);
      acc[2][3] = fmaf(a2, b3, acc[2][3]);
      acc[3][0] = fmaf(a3, b0, acc[3][0]);
      acc[3][1] = fmaf(a3, b1, acc[3][1]);
      acc[3][2] = fmaf(a3, b2, acc[3][2]);
      acc[3][3] = fmaf(a3, b3, acc[3][3]);
    }
    __syncthreads();
  }

#pragma unroll
  for (int i = 0; i < 4; ++i) {
    if (m0 + tm + i < M) {
      *(float4*)&C[(size_t)(m0 + tm + i) * HF + n0 + tn] =
          make_float4(acc[i][0], acc[i][1], acc[i][2], acc[i][3]);
    }
  }
}

// ---------------------------------------------------------------------------
// Kernel 2: el[n,h] = sum_f feat_src[n,h,f] * attn_l[h,f]
// (er is skipped: it cancels exactly in the edge softmax)
// ---------------------------------------------------------------------------
__global__ void scores_kernel(const float* __restrict__ feat_src,
                              const float* __restrict__ attn_l,
                              float* __restrict__ el, int NH) {
  int idx = blockIdx.x * blockDim.x + threadIdx.x;
  if (idx >= NH) return;
  int h = idx & (HEADS - 1);
  const float4* fp = (const float4*)(feat_src + (size_t)idx * OUT_F);
  const float4* ap = (const float4*)(attn_l + h * OUT_F);
  float acc = 0.f;
#pragma unroll
  for (int q = 0; q < OUT_F / 4; ++q) {
    float4 fv = fp[q], av = ap[q];
    acc += fv.x * av.x + fv.y * av.y + fv.z * av.z + fv.w * av.w;
  }
  el[idx] = acc;
}

// ---------------------------------------------------------------------------
// Kernel 3: CSR row_ptr from sorted dst via binary search
// ---------------------------------------------------------------------------
__global__ void rowptr_kernel(const int* __restrict__ dst,
                              int* __restrict__ row_ptr, int N, int E) {
  int i = blockIdx.x * blockDim.x + threadIdx.x;
  if (i > N) return;
  int lo = 0, hi = E;
  while (lo < hi) {
    int mid = (lo + hi) >> 1;
    if (dst[mid] < i) lo = mid + 1; else hi = mid;
  }
  row_ptr[i] = lo;
}

// ---------------------------------------------------------------------------
// Kernel 4: per-destination softmax + weighted aggregation.
// One block (256 threads) per node. Thread t owns output (h=t>>5, f=t&31).
// ---------------------------------------------------------------------------
#define CHUNK 64

__global__ __launch_bounds__(256) void aggregate_kernel(
    const float* __restrict__ feat_src, const float* __restrict__ el,
    const int* __restrict__ src, const int* __restrict__ row_ptr,
    float* __restrict__ out) {
  const int v = blockIdx.x;
  const int t = threadIdx.x;
  const int beg = row_ptr[v];
  const int deg = row_ptr[v + 1] - beg;

  if (deg == 0) {  // no incoming edges: segment_sum of nothing = 0
    out[(size_t)v * HF + t] = 0.f;
    return;
  }

  __shared__ float s_part[32][HEADS];
  __shared__ float s_m[HEADS];
  __shared__ float s_inv[HEADS];
  __shared__ float s_alpha[CHUNK][HEADS];
  __shared__ int s_src[CHUNK];

  const int h8 = t & 7;   // head for gather phases
  const int j = t >> 3;   // 0..31

  // Phase 1: m[h] = max_e el[src[e], h]
  float mx = -1e30f;
  for (int e = j; e < deg; e += 32) {
    int s = src[beg + e];
    mx = fmaxf(mx, el[s * HEADS + h8]);
  }
  s_part[j][h8] = mx;
  __syncthreads();
  if (t < HEADS) {
    float m = s_part[0][t];
#pragma unroll
    for (int jj = 1; jj < 32; ++jj) m = fmaxf(m, s_part[jj][t]);
    s_m[t] = m;
  }
  __syncthreads();

  // Phase 2: s[h] = sum_e exp(leaky_relu(el - m))
  const float m = s_m[h8];
  float sm = 0.f;
  for (int e = j; e < deg; e += 32) {
    int s = src[beg + e];
    float z = el[s * HEADS + h8] - m;
    float w = (z >= 0.f) ? z : SLOPE * z;
    sm += __expf(w);
  }
  s_part[j][h8] = sm;
  __syncthreads();
  if (t < HEADS) {
    float a = 0.f;
#pragma unroll
    for (int jj = 0; jj < 32; ++jj) a += s_part[jj][t];
    s_inv[t] = 1.0f / a;
  }
  __syncthreads();

  // Phase 3: out[v,h,f] = sum_e alpha[e,h] * feat_src[src[e],h,f]
  const int h = t >> 5;
  const float inv = s_inv[h8];
  float acc = 0.f;
  for (int c0 = 0; c0 < deg; c0 += CHUNK) {
    int cn = min(CHUNK, deg - c0);
    __syncthreads();  // protect s_alpha/s_src from previous iteration readers
    for (int c = j; c < cn; c += 32) {
      int s = src[beg + c0 + c];
      if (h8 == 0) s_src[c] = s;
      float z = el[s * HEADS + h8] - m;
      float w = (z >= 0.f) ? z : SLOPE * z;
      s_alpha[c][h8] = __expf(w) * inv;
    }
    __syncthreads();
    for (int c = 0; c < cn; ++c) {
      acc = fmaf(s_alpha[c][h], feat_src[(size_t)s_src[c] * HF + t], acc);
    }
  }
  out[(size_t)v * HF + t] = acc;
}

// ---------------------------------------------------------------------------
extern "C" void kernel_launch(void* const* d_in, const int* in_sizes, int n_in,
                              void* d_out, int out_size, void* d_ws,
                              size_t ws_size, hipStream_t stream) {
  const float* feat = (const float*)d_in[0];
  const float* fc_w = (const float*)d_in[1];
  const float* attn_l = (const float*)d_in[2];
  // d_in[3] = attn_r: unused — cancels exactly in the edge softmax.
  const int* src = (const int*)d_in[4];
  const int* dst = (const int*)d_in[5];
  float* out = (float*)d_out;

  const int N = N_NODES;
  const int E = N_EDGES;

  // workspace layout
  float* feat_src = (float*)d_ws;                    // N*256 floats (51.2 MB)
  float* el = feat_src + (size_t)N * HF;             // N*8 floats
  int* row_ptr = (int*)(el + (size_t)N * HEADS);     // N+1 ints

  dim3 gemm_grid(HF / BN, (N + BM - 1) / BM);
  gemm_kernel<<<gemm_grid, 256, 0, stream>>>(feat, fc_w, feat_src, N);

  scores_kernel<<<(N * HEADS + 255) / 256, 256, 0, stream>>>(feat_src, attn_l,
                                                             el, N * HEADS);

  rowptr_kernel<<<(N + 1 + 255) / 256, 256, 0, stream>>>(dst, row_ptr, N, E);

  aggregate_kernel<<<N, 256, 0, stream>>>(feat_src, el, src, row_ptr, out);
}

// Round 2
// 279.725 us; speedup vs baseline: 1.2649x; 1.2649x over previous
//
#include <hip/hip_runtime.h>
#include <hip/hip_bf16.h>

#define N_NODES 50000
#define N_EDGES 800000
#define IN_F 256
#define HEADS 8
#define OUT_F 32
#define HF (HEADS * OUT_F)   // 256
#define SLOPE 0.2f

typedef __attribute__((ext_vector_type(8))) short bf16x8;
typedef __attribute__((ext_vector_type(4))) float f32x4;

__device__ __forceinline__ ushort f2bf(float f) {
  union { float f; unsigned u; } x;
  x.f = f;
  unsigned r = x.u + 0x7FFFu + ((x.u >> 16) & 1u);  // RNE
  return (ushort)(r >> 16);
}

__device__ __forceinline__ float bf2f(ushort u) {
  union { unsigned u; float f; } x;
  x.u = ((unsigned)u) << 16;
  return x.f;
}

// ---------------------------------------------------------------------------
// Kernel 1: bf16 MFMA GEMM  Cb[M,256](bf16) = A[M,256](f32) @ B[256,256](f32)
// 64x64 tile, BK=32, 256 threads = 4 waves, 2x2 16x16x32 fragments per wave.
// fp32 -> bf16 conversion happens during LDS staging.
// ---------------------------------------------------------------------------
#define GBM 64
#define GBN 64
#define GBK 32
#define LDA 40   // padded LDS row stride (bf16 elems): 80 B, 16B-aligned

__global__ __launch_bounds__(256) void gemm_mfma(
    const float* __restrict__ A, const float* __restrict__ B,
    ushort* __restrict__ Cb, int M) {
  __shared__ __align__(16) ushort As[GBM * LDA];  // [m][k]
  __shared__ __align__(16) ushort Bs[GBN * LDA];  // [n][k]

  const int t = threadIdx.x;
  const int wave = t >> 6;
  const int lane = t & 63;
  const int m0 = blockIdx.y * GBM;
  const int n0 = blockIdx.x * GBN;

  // staging indices
  const int ar = t >> 2;         // A row 0..63
  const int ak = (t & 3) * 8;    // A k-offset {0,8,16,24}
  const int bk = t >> 3;         // B k-row 0..31
  const int bn = (t & 7) * 8;    // B n-offset {0,..,56}

  // compute indices
  const int q = lane >> 4;       // quad 0..3
  const int l16 = lane & 15;
  const int wm = (wave >> 1) * 32;  // 0 or 32
  const int wn = (wave & 1) * 32;   // 0 or 32

  f32x4 acc[2][2] = {};

  for (int k0 = 0; k0 < IN_F; k0 += GBK) {
    // --- stage A tile (64 x 32), convert fp32->bf16
    {
      float4 v0 = make_float4(0.f, 0.f, 0.f, 0.f);
      float4 v1 = make_float4(0.f, 0.f, 0.f, 0.f);
      if (m0 + ar < M) {
        const float* ap = &A[(size_t)(m0 + ar) * IN_F + k0 + ak];
        v0 = *(const float4*)ap;
        v1 = *(const float4*)(ap + 4);
      }
      union { ushort s[8]; uint4 v; } u;
      u.s[0] = f2bf(v0.x); u.s[1] = f2bf(v0.y);
      u.s[2] = f2bf(v0.z); u.s[3] = f2bf(v0.w);
      u.s[4] = f2bf(v1.x); u.s[5] = f2bf(v1.y);
      u.s[6] = f2bf(v1.z); u.s[7] = f2bf(v1.w);
      *(uint4*)&As[ar * LDA + ak] = u.v;
    }
    // --- stage B tile (32 x 64) transposed into Bs[n][k]
    {
      const float* bp = &B[(size_t)(k0 + bk) * HF + n0 + bn];
      float4 v0 = *(const float4*)bp;
      float4 v1 = *(const float4*)(bp + 4);
      Bs[(bn + 0) * LDA + bk] = f2bf(v0.x);
      Bs[(bn + 1) * LDA + bk] = f2bf(v0.y);
      Bs[(bn + 2) * LDA + bk] = f2bf(v0.z);
      Bs[(bn + 3) * LDA + bk] = f2bf(v0.w);
      Bs[(bn + 4) * LDA + bk] = f2bf(v1.x);
      Bs[(bn + 5) * LDA + bk] = f2bf(v1.y);
      Bs[(bn + 6) * LDA + bk] = f2bf(v1.z);
      Bs[(bn + 7) * LDA + bk] = f2bf(v1.w);
    }
    __syncthreads();

    // --- compute: A frag A[m=l16][k=q*8+j], B frag B[k=q*8+j][n=l16]
    bf16x8 aF[2], bF[2];
    aF[0] = *(const bf16x8*)&As[(wm + 0 + l16) * LDA + q * 8];
    aF[1] = *(const bf16x8*)&As[(wm + 16 + l16) * LDA + q * 8];
    bF[0] = *(const bf16x8*)&Bs[(wn + 0 + l16) * LDA + q * 8];
    bF[1] = *(const bf16x8*)&Bs[(wn + 16 + l16) * LDA + q * 8];
#pragma unroll
    for (int i = 0; i < 2; ++i)
#pragma unroll
      for (int j = 0; j < 2; ++j)
        acc[i][j] = __builtin_amdgcn_mfma_f32_16x16x32_bf16(
            aF[i], bF[j], acc[i][j], 0, 0, 0);
    __syncthreads();
  }

  // --- epilogue: C/D layout col=l16, row=q*4+reg; store bf16
#pragma unroll
  for (int i = 0; i < 2; ++i) {
#pragma unroll
    for (int r = 0; r < 4; ++r) {
      const int row = m0 + wm + 16 * i + q * 4 + r;
      if (row < M) {
#pragma unroll
        for (int j = 0; j < 2; ++j) {
          const int col = n0 + wn + 16 * j + l16;
          Cb[(size_t)row * HF + col] = f2bf(acc[i][j][r]);
        }
      }
    }
  }
}

// ---------------------------------------------------------------------------
// Kernel 2: wl[k,h] = sum_f fc_w[k, h*32+f] * attn_l[h,f]   (256x8, exact fp32)
// ---------------------------------------------------------------------------
__global__ void wl_kernel(const float* __restrict__ fc_w,
                          const float* __restrict__ attn_l,
                          float* __restrict__ wl) {
  const int idx = blockIdx.x * blockDim.x + threadIdx.x;  // 0..2047
  const int k = idx >> 3;
  const int h = idx & 7;
  const float* fp = &fc_w[(size_t)k * HF + h * OUT_F];
  const float* ap = &attn_l[h * OUT_F];
  float acc = 0.f;
#pragma unroll
  for (int f = 0; f < OUT_F; f += 4) {
    float4 a = *(const float4*)&fp[f];
    float4 b = *(const float4*)&ap[f];
    acc += a.x * b.x + a.y * b.y + a.z * b.z + a.w * b.w;
  }
  wl[idx] = acc;
}

// ---------------------------------------------------------------------------
// Kernel 3: el[n,h] = sum_k feat[n,k] * wl[k,h]   (fp32-exact softmax scores)
// ---------------------------------------------------------------------------
__global__ __launch_bounds__(256) void el_kernel(
    const float* __restrict__ feat, const float* __restrict__ wl,
    float* __restrict__ el, int NH) {
  __shared__ float wls[IN_F * HEADS];  // 8 KB
  const int t = threadIdx.x;
#pragma unroll
  for (int i = 0; i < (IN_F * HEADS) / 256; ++i)
    wls[i * 256 + t] = wl[i * 256 + t];
  __syncthreads();

  const int idx = blockIdx.x * 256 + t;
  if (idx >= NH) return;
  const int n = idx >> 3;
  const int h = idx & 7;
  const float* fp = &feat[(size_t)n * IN_F];
  float acc = 0.f;
#pragma unroll 8
  for (int k0 = 0; k0 < IN_F; k0 += 4) {
    float4 v = *(const float4*)&fp[k0];
    acc += v.x * wls[(k0 + 0) * 8 + h] + v.y * wls[(k0 + 1) * 8 + h] +
           v.z * wls[(k0 + 2) * 8 + h] + v.w * wls[(k0 + 3) * 8 + h];
  }
  el[idx] = acc;
}

// ---------------------------------------------------------------------------
// Kernel 4: CSR row_ptr from sorted dst via binary search
// ---------------------------------------------------------------------------
__global__ void rowptr_kernel(const int* __restrict__ dst,
                              int* __restrict__ row_ptr, int N, int E) {
  int i = blockIdx.x * blockDim.x + threadIdx.x;
  if (i > N) return;
  int lo = 0, hi = E;
  while (lo < hi) {
    int mid = (lo + hi) >> 1;
    if (dst[mid] < i) lo = mid + 1; else hi = mid;
  }
  row_ptr[i] = lo;
}

// ---------------------------------------------------------------------------
// Kernel 5: per-destination softmax + weighted aggregation (bf16 gather).
// One block (256 threads) per node. Thread t owns (h=t>>5, f=t&31).
// Softmax sum merged into the accumulation pass; normalize at the end.
// ---------------------------------------------------------------------------
#define CHUNK 64

__global__ __launch_bounds__(256) void aggregate_kernel(
    const ushort* __restrict__ featb, const float* __restrict__ el,
    const int* __restrict__ src, const int* __restrict__ row_ptr,
    float* __restrict__ out) {
  const int v = blockIdx.x;
  const int t = threadIdx.x;
  const int beg = row_ptr[v];
  const int deg = row_ptr[v + 1] - beg;

  if (deg == 0) {  // segment_sum over empty segment = 0
    out[(size_t)v * HF + t] = 0.f;
    return;
  }

  __shared__ float s_part[32][HEADS];
  __shared__ float s_m[HEADS];
  __shared__ float s_inv[HEADS];
  __shared__ float s_alpha[CHUNK][HEADS];
  __shared__ int s_src[CHUNK];

  const int h8 = t & 7;   // head for gather phases
  const int j = t >> 3;   // 0..31
  const int h = t >> 5;   // head owned for output

  // Phase 1: m[h] = max over incoming edges of el[src[e], h]
  float mx = -1e30f;
  for (int e = j; e < deg; e += 32) {
    int s = src[beg + e];
    mx = fmaxf(mx, el[s * HEADS + h8]);
  }
  s_part[j][h8] = mx;
  __syncthreads();
  if (t < HEADS) {
    float m = s_part[0][t];
#pragma unroll
    for (int jj = 1; jj < 32; ++jj) m = fmaxf(m, s_part[jj][t]);
    s_m[t] = m;
  }
  __syncthreads();

  // Phase 2: accumulate unnormalized coeff-weighted features + coeff sums
  const float m = s_m[h8];
  float acc = 0.f;
  float ssum = 0.f;  // per-(j,h8) partial coeff sum
  for (int c0 = 0; c0 < deg; c0 += CHUNK) {
    const int cn = min(CHUNK, deg - c0);
    __syncthreads();  // protect s_alpha/s_src from previous iteration readers
    for (int c = j; c < cn; c += 32) {
      int s = src[beg + c0 + c];
      if (h8 == 0) s_src[c] = s;
      float z = el[s * HEADS + h8] - m;
      float w = (z >= 0.f) ? z : SLOPE * z;
      float cf = __expf(w);
      s_alpha[c][h8] = cf;
      ssum += cf;
    }
    __syncthreads();
    if (cn == CHUNK) {
#pragma unroll 8
      for (int c = 0; c < CHUNK; ++c)
        acc = fmaf(s_alpha[c][h], bf2f(featb[(size_t)s_src[c] * HF + t]), acc);
    } else {
#pragma unroll 4
      for (int c = 0; c < cn; ++c)
        acc = fmaf(s_alpha[c][h], bf2f(featb[(size_t)s_src[c] * HF + t]), acc);
    }
  }

  // Reduce coeff sums -> 1/s per head
  s_part[j][h8] = ssum;
  __syncthreads();
  if (t < HEADS) {
    float a = 0.f;
#pragma unroll
    for (int jj = 0; jj < 32; ++jj) a += s_part[jj][t];
    s_inv[t] = 1.0f / a;
  }
  __syncthreads();

  out[(size_t)v * HF + t] = acc * s_inv[h];
}

// ---------------------------------------------------------------------------
extern "C" void kernel_launch(void* const* d_in, const int* in_sizes, int n_in,
                              void* d_out, int out_size, void* d_ws,
                              size_t ws_size, hipStream_t stream) {
  const float* feat = (const float*)d_in[0];
  const float* fc_w = (const float*)d_in[1];
  const float* attn_l = (const float*)d_in[2];
  // d_in[3] = attn_r: unused — cancels exactly in the edge softmax.
  const int* src = (const int*)d_in[4];
  const int* dst = (const int*)d_in[5];
  float* out = (float*)d_out;

  const int N = N_NODES;
  const int E = N_EDGES;

  // workspace layout
  ushort* featb = (ushort*)d_ws;                       // N*256 bf16 (25.6 MB)
  float* el = (float*)(featb + (size_t)N * HF);        // N*8 f32
  float* wl = el + (size_t)N * HEADS;                  // 256*8 f32
  int* row_ptr = (int*)(wl + IN_F * HEADS);            // N+1 ints

  dim3 gemm_grid(HF / GBN, (N + GBM - 1) / GBM);
  gemm_mfma<<<gemm_grid, 256, 0, stream>>>(feat, fc_w, featb, N);

  wl_kernel<<<(IN_F * HEADS) / 256, 256, 0, stream>>>(fc_w, attn_l, wl);

  el_kernel<<<(N * HEADS + 255) / 256, 256, 0, stream>>>(feat, wl, el,
                                                         N * HEADS);

  rowptr_kernel<<<(N + 1 + 255) / 256, 256, 0, stream>>>(dst, row_ptr, N, E);

  aggregate_kernel<<<N, 256, 0, stream>>>(featb, el, src, row_ptr, out);
}